// Round 7
// baseline (10516.212 us; speedup 1.0000x reference)
//
#include <hip/hip_runtime.h>
#include <hip/hip_cooperative_groups.h>

namespace cg = cooperative_groups;

#define NN 2048
#define NB 32
#define NT 500
#define WGS 1024
#define NWG 256

// Persistent cooperative kernel, ONE dispatch. Per-step cross-WG exchange via
// fence-free tagged atomics: each spike word is a 64-bit (tag<<32 | bits32)
// published with a RELAXED agent-scope atomic store and polled with RELAXED
// agent-scope atomic loads. No __threadfence, no acquire/release in the hot
// loop -> no XCD-L2 invalidation (R4's 105 GB lesson), W stays L2-resident.
//
// Safety: tag+payload share one atomic word (no ordering needed). Double
// buffer by parity; slot for tag s+1 is only overwritten after all WGs have
// finished consuming tag s-1 (publish of s+1 requires owner read-complete of
// step s, which requires every WG's tag-s publish, which follows their s-1
// read-complete). Stale tags from prior replays are overwritten by owner init
// (buffer0: tag0/zeros, buffer1: sentinel) before one cg grid.sync.
//
// Compute body bit-identical to R6 (validated): WG owns 8 rows, thread
// (rh,jh,b) does 2 rows x 256-j sequential chunk; chunks combined 0..7 in
// order by the (row,b) owner. mem/cnt in registers (persistent kernel).
//
// ws: bitsG2 u64[2][2048] @0 (32 KB) | xT f32[500][32] @32768 | wgpart @98304

__launch_bounds__(WGS, 4)
__global__ void reservoir_kernel(const float* __restrict__ x,
                                 const float* __restrict__ W,
                                 const float* __restrict__ bias,
                                 float* __restrict__ out,
                                 void* __restrict__ wsv)
{
    cg::grid_group grid = cg::this_grid();

    __shared__ unsigned int lbits[NN];      // 8 KB spike bits
    __shared__ float lpart[8][8][32];       // 8 KB [jh][row][b]
    __shared__ float lout[2][NB][9];        // padded output stage
    __shared__ int   lcnt[4];

    unsigned long long* bitsG2 = (unsigned long long*)wsv;          // [2][2048]
    float* xT    = (float*)((char*)wsv + 32768);                    // [500][32]
    int*   wgpart = (int*)((char*)wsv + 98304);                     // [256]

    const int wg = blockIdx.x;
    const int t  = threadIdx.x;
    const int i0 = wg * 8;

    // owner init of this WG's spike words (kills stale tags from prior replays)
    if (t < 8) {
        __hip_atomic_store(&bitsG2[i0 + t], 0ull,
                           __ATOMIC_RELAXED, __HIP_MEMORY_SCOPE_AGENT);
        __hip_atomic_store(&bitsG2[NN + i0 + t], 0xFFFFFFFF00000000ull,
                           __ATOMIC_RELAXED, __HIP_MEMORY_SCOPE_AGENT);
    }
    // x transpose -> xT[step][b]
    for (int g = wg * WGS + t; g < NT * NB; g += NWG * WGS)
        xT[g] = x[(size_t)(g & 31) * NT + (g >> 5)];

    // compute identity: 2 rows per thread
    const int rh = t >> 8;          // 0..3 -> rows 2rh, 2rh+1
    const int jh = (t >> 5) & 7;    // chunk 0..7
    const int b  = t & 31;          // batch

    const float4* __restrict__ wr0 = (const float4*)(W + (size_t)(i0 + 2 * rh    ) * NN) + jh * 64;
    const float4* __restrict__ wr1 = (const float4*)(W + (size_t)(i0 + 2 * rh + 1) * NN) + jh * 64;

    // combine identity (t < 256): (row cil, batch cb), state in registers
    const int cil = t >> 5;
    const int cb  = t & 31;
    const float biasv = (t < 256) ? bias[i0 + cil] : 0.0f;
    float mem = 0.0f;
    int   cnt = 0;

    float* spk_rec = out + 1;
    float* mem_rec = out + 1 + (size_t)NT * NB * NN;

    grid.sync();   // init visibility (once)

    for (int step = 0; step < NT; ++step) {
        const int cur = step & 1;
        const unsigned int tag = (unsigned int)step;
        const unsigned long long* src = bitsG2 + (size_t)cur * NN;

        // poll+stage spike bits (2 words/thread, coalesced, relaxed atomics)
        {
            unsigned long long v;
            for (;;) {
                v = __hip_atomic_load(&src[t], __ATOMIC_RELAXED,
                                      __HIP_MEMORY_SCOPE_AGENT);
                if ((unsigned int)(v >> 32) == tag) break;
                __builtin_amdgcn_s_sleep(1);
            }
            lbits[t] = (unsigned int)v;
            for (;;) {
                v = __hip_atomic_load(&src[t + 1024], __ATOMIC_RELAXED,
                                      __HIP_MEMORY_SCOPE_AGENT);
                if ((unsigned int)(v >> 32) == tag) break;
                __builtin_amdgcn_s_sleep(1);
            }
            lbits[t + 1024] = (unsigned int)v;
        }
        const float xv = (t < 256) ? xT[step * NB + cb] : 0.0f;
        __syncthreads();

        // chunk partial: 2 rows x 1 batch over 256 consecutive j (bit-exact order)
        float c0 = 0.0f, c1 = 0.0f;
        const uint4* bp = ((const uint4*)lbits) + jh * 64;
        #pragma unroll 4
        for (int jj = 0; jj < 64; ++jj) {
            const float4 w0 = wr0[jj];
            const float4 w1 = wr1[jj];
            const uint4  bu = bp[jj];
            float s;
            s = (float)((bu.x >> b) & 1u); c0 = fmaf(w0.x, s, c0); c1 = fmaf(w1.x, s, c1);
            s = (float)((bu.y >> b) & 1u); c0 = fmaf(w0.y, s, c0); c1 = fmaf(w1.y, s, c1);
            s = (float)((bu.z >> b) & 1u); c0 = fmaf(w0.z, s, c0); c1 = fmaf(w1.z, s, c1);
            s = (float)((bu.w >> b) & 1u); c0 = fmaf(w0.w, s, c0); c1 = fmaf(w1.w, s, c1);
        }
        lpart[jh][2 * rh    ][b] = c0;
        lpart[jh][2 * rh + 1][b] = c1;
        __syncthreads();

        if (t < 256) {
            // sequential combine over chunks (bit-exact R3/R5/R6 order)
            float d = lpart[0][cil][cb];
            #pragma unroll
            for (int k = 1; k < 8; ++k) d += lpart[k][cil][cb];

            const float sp = (float)((lbits[i0 + cil] >> cb) & 1u);

            float base = 0.95f * mem + xv + d + biasv;
            float nm   = base * (1.0f - sp);
            float ns   = (nm > 1.0f) ? 1.0f : 0.0f;
            mem = nm;
            cnt += (int)ns;

            // publish spike words for next step (tag = step+1, relaxed atomics)
            unsigned long long bal = __ballot(ns > 0.5f);
            unsigned long long* dst = bitsG2 + (size_t)(1 - cur) * NN;
            const unsigned long long tg = ((unsigned long long)(step + 1)) << 32;
            const int l  = t & 63;
            const int w2 = t >> 6;
            if (l == 0)
                __hip_atomic_store(&dst[i0 + 2 * w2],
                                   tg | (unsigned int)(bal & 0xFFFFFFFFull),
                                   __ATOMIC_RELAXED, __HIP_MEMORY_SCOPE_AGENT);
            if (l == 32)
                __hip_atomic_store(&dst[i0 + 2 * w2 + 1],
                                   tg | (unsigned int)(bal >> 32),
                                   __ATOMIC_RELAXED, __HIP_MEMORY_SCOPE_AGENT);
            if (l == 0) lcnt[w2] = __popcll(bal);

            lout[0][cb][cil] = ns;
            lout[1][cb][cil] = nm;
        }
        __syncthreads();

        // record stores (8 consecutive floats per (step,b)), WG-private data
        if (t < 512) {
            const int arr = t >> 8;
            const int r2  = t & 255;
            const int bb  = r2 >> 3;
            const int il  = r2 & 7;
            size_t o = ((size_t)step * NB + bb) * (size_t)NN + i0 + il;
            if (arr == 0) __builtin_nontemporal_store(lout[0][bb][il], &spk_rec[o]);
            else          __builtin_nontemporal_store(lout[1][bb][il], &mem_rec[o]);
        }
    }

    // average firing rate (cnt==0 for t>=256)
    #pragma unroll
    for (int d2 = 1; d2 < 64; d2 <<= 1) cnt += __shfl_xor(cnt, d2, 64);
    if ((t & 63) == 0 && t < 256) lcnt[t >> 6] = cnt;
    __syncthreads();
    if (t == 0) wgpart[wg] = lcnt[0] + lcnt[1] + lcnt[2] + lcnt[3];
    grid.sync();
    if (wg == 0) {
        int ps = (t < NWG) ? wgpart[t] : 0;
        #pragma unroll
        for (int d2 = 1; d2 < 64; d2 <<= 1) ps += __shfl_xor(ps, d2, 64);
        if ((t & 63) == 0 && t < 256) lcnt[t >> 6] = ps;
        __syncthreads();
        if (t == 0) {
            long long s2 = (long long)lcnt[0] + lcnt[1] + lcnt[2] + lcnt[3];
            out[0] = (float)((double)s2 / (double)((long long)NT * NB * NN));
        }
    }
}

extern "C" void kernel_launch(void* const* d_in, const int* in_sizes, int n_in,
                              void* d_out, int out_size, void* d_ws, size_t ws_size,
                              hipStream_t stream) {
    const float* x    = (const float*)d_in[0];  // (32, 500, 1)
    const float* W    = (const float*)d_in[1];  // (2048, 2048)
    const float* bias = (const float*)d_in[2];  // (2048,)
    float* out = (float*)d_out;
    void*  ws  = d_ws;

    void* args[] = { (void*)&x, (void*)&W, (void*)&bias, (void*)&out, (void*)&ws };
    hipLaunchCooperativeKernel((const void*)reservoir_kernel,
                               dim3(NWG), dim3(WGS), args, 0, stream);
}

// Round 8
// 9788.005 us; speedup vs baseline: 1.0744x; 1.0744x over previous
//
#include <hip/hip_runtime.h>
#include <hip/hip_cooperative_groups.h>

namespace cg = cooperative_groups;

#define NN 2048
#define NB 32
#define NT 500
#define WGS 1024
#define NWG 256

// Persistent cooperative kernel, one dispatch. R8 exchange: plain u64 spike
// payloads (2 rows x 32 batches = one publishing wave's ballot) + per-
// producer-wave epoch array ep[1024] (u32, monotonic "data for step S ready").
// Consumer thread t polls ep[t] (4B coalesced) then one u64 load. Producer
// wave: data store -> wave-local s_waitcnt vmcnt(0) (release, NO cache fence,
// no L2 invalidate -- R4 lesson) -> epoch store. All sc-bypass relaxed agent
// ops; W stays L2-resident.
//
// Safety: WG publishes s+1 only after observing ALL ep >= s (its (B)/(C)
// barriers order this), which transitively implies every WG finished reading
// buf[(s-1)&1] -- the buffer s+1 overwrites. Replay-safe: ep/buf0 re-inited
// before one cg grid.sync.
//
// Compute body bit-identical to R6/R7 (validated): WG owns 8 rows, thread
// (rh,jh,b) does 2 rows x 256-j sequential chunk; chunks combined 0..7 in
// order by the (row,b) owner.
//
// ws: data64 u64[2][1024] @0 | ep u32[1024] @16384 | xT @20480 | wgpart @86016

__launch_bounds__(WGS, 4)
__global__ void reservoir_kernel(const float* __restrict__ x,
                                 const float* __restrict__ W,
                                 const float* __restrict__ bias,
                                 float* __restrict__ out,
                                 void* __restrict__ wsv)
{
    cg::grid_group grid = cg::this_grid();

    __shared__ unsigned int lbits[NN];      // 8 KB spike bits
    __shared__ float lpart[8][8][32];       // 8 KB [jh][row][b]
    __shared__ float lout[2][NB][9];        // padded output stage
    __shared__ int   lcnt[4];

    unsigned long long* data64 = (unsigned long long*)wsv;          // [2][1024]
    unsigned int* ep  = (unsigned int*)((char*)wsv + 16384);        // [1024]
    float* xT         = (float*)((char*)wsv + 20480);               // [500][32]
    int*   wgpart     = (int*)((char*)wsv + 86016);                 // [256]

    const int wg = blockIdx.x;
    const int t  = threadIdx.x;
    const int i0 = wg * 8;

    // init: step-0 spike buffer + epochs (kills stale state across replays)
    {
        int g = wg * WGS + t;
        if (g < 1024) {
            __hip_atomic_store(&data64[g], 0ull,
                               __ATOMIC_RELAXED, __HIP_MEMORY_SCOPE_AGENT);
            __hip_atomic_store(&ep[g], 0u,
                               __ATOMIC_RELAXED, __HIP_MEMORY_SCOPE_AGENT);
        }
        for (; g < NT * NB; g += NWG * WGS)
            xT[g] = x[(size_t)(g & 31) * NT + (g >> 5)];
    }

    // compute identity: 2 rows per thread (== R7)
    const int rh = t >> 8;          // 0..3 -> rows 2rh, 2rh+1
    const int jh = (t >> 5) & 7;    // chunk 0..7
    const int b  = t & 31;          // batch

    const float4* __restrict__ wr0 = (const float4*)(W + (size_t)(i0 + 2 * rh    ) * NN) + jh * 64;
    const float4* __restrict__ wr1 = (const float4*)(W + (size_t)(i0 + 2 * rh + 1) * NN) + jh * 64;

    // combine identity (t < 256): (row cil, batch cb), state in registers
    const int cil = t >> 5;
    const int cb  = t & 31;
    const float biasv = (t < 256) ? bias[i0 + cil] : 0.0f;
    float mem = 0.0f;
    int   cnt = 0;

    float* spk_rec = out + 1;
    float* mem_rec = out + 1 + (size_t)NT * NB * NN;

    grid.sync();   // init visibility (once)

    for (int step = 0; step < NT; ++step) {
        const int cur = step & 1;

        // xv in flight early
        const float xv = (t < 256) ? xT[step * NB + cb] : 0.0f;

        // poll own producer-wave epoch, then ONE u64 bulk load (per-producer trickle)
        {
            for (;;) {
                unsigned int e = __hip_atomic_load(&ep[t], __ATOMIC_RELAXED,
                                                   __HIP_MEMORY_SCOPE_AGENT);
                if (e >= (unsigned int)step) break;
                __builtin_amdgcn_s_sleep(1);
            }
            unsigned long long v =
                __hip_atomic_load(&data64[(size_t)cur * 1024 + t],
                                  __ATOMIC_RELAXED, __HIP_MEMORY_SCOPE_AGENT);
            *(unsigned long long*)&lbits[2 * t] = v;   // ds_write_b64
        }
        __syncthreads();   // (B) lbits ready

        // chunk partial: 2 rows x 1 batch over 256 consecutive j (bit-exact order)
        float c0 = 0.0f, c1 = 0.0f;
        const uint4* bp = ((const uint4*)lbits) + jh * 64;
        #pragma unroll 4
        for (int jj = 0; jj < 64; ++jj) {
            const float4 w0 = wr0[jj];
            const float4 w1 = wr1[jj];
            const uint4  bu = bp[jj];
            float s;
            s = (float)((bu.x >> b) & 1u); c0 = fmaf(w0.x, s, c0); c1 = fmaf(w1.x, s, c1);
            s = (float)((bu.y >> b) & 1u); c0 = fmaf(w0.y, s, c0); c1 = fmaf(w1.y, s, c1);
            s = (float)((bu.z >> b) & 1u); c0 = fmaf(w0.z, s, c0); c1 = fmaf(w1.z, s, c1);
            s = (float)((bu.w >> b) & 1u); c0 = fmaf(w0.w, s, c0); c1 = fmaf(w1.w, s, c1);
        }
        lpart[jh][2 * rh    ][b] = c0;
        lpart[jh][2 * rh + 1][b] = c1;
        __syncthreads();   // (C)

        if (t < 256) {
            // sequential combine over chunks (bit-exact R3/R5/R6/R7 order)
            float d = lpart[0][cil][cb];
            #pragma unroll
            for (int k = 1; k < 8; ++k) d += lpart[k][cil][cb];

            const float sp = (float)((lbits[i0 + cil] >> cb) & 1u);

            float base = 0.95f * mem + xv + d + biasv;
            float nm   = base * (1.0f - sp);
            float ns   = (nm > 1.0f) ? 1.0f : 0.0f;
            mem = nm;
            cnt += (int)ns;

            // publish: data u64 -> wave-local release (vmcnt) -> epoch
            unsigned long long bal = __ballot(ns > 0.5f);   // low32=row 2w2, high32=row 2w2+1
            const int l  = t & 63;
            const int w2 = t >> 6;
            if (l == 0)
                __hip_atomic_store(&data64[(size_t)(1 - cur) * 1024 + 4 * wg + w2],
                                   bal, __ATOMIC_RELAXED, __HIP_MEMORY_SCOPE_AGENT);
            asm volatile("s_waitcnt vmcnt(0)" ::: "memory");
            if (l == 0)
                __hip_atomic_store(&ep[4 * wg + w2], (unsigned int)(step + 1),
                                   __ATOMIC_RELAXED, __HIP_MEMORY_SCOPE_AGENT);

            lout[0][cb][cil] = ns;
            lout[1][cb][cil] = nm;
        }
        __syncthreads();   // (D) lout staged (after epoch publish -> off critical path)

        // record stores (8 consecutive floats per (step,b))
        if (t < 512) {
            const int arr = t >> 8;
            const int r2  = t & 255;
            const int bb  = r2 >> 3;
            const int il  = r2 & 7;
            size_t o = ((size_t)step * NB + bb) * (size_t)NN + i0 + il;
            if (arr == 0) __builtin_nontemporal_store(lout[0][bb][il], &spk_rec[o]);
            else          __builtin_nontemporal_store(lout[1][bb][il], &mem_rec[o]);
        }
    }

    // average firing rate (cnt==0 for t>=256)
    #pragma unroll
    for (int d2 = 1; d2 < 64; d2 <<= 1) cnt += __shfl_xor(cnt, d2, 64);
    if ((t & 63) == 0 && t < 256) lcnt[t >> 6] = cnt;
    __syncthreads();
    if (t == 0) wgpart[wg] = lcnt[0] + lcnt[1] + lcnt[2] + lcnt[3];
    grid.sync();
    if (wg == 0) {
        int ps = (t < NWG) ? wgpart[t] : 0;
        #pragma unroll
        for (int d2 = 1; d2 < 64; d2 <<= 1) ps += __shfl_xor(ps, d2, 64);
        if ((t & 63) == 0 && t < 256) lcnt[t >> 6] = ps;
        __syncthreads();
        if (t == 0) {
            long long s2 = (long long)lcnt[0] + lcnt[1] + lcnt[2] + lcnt[3];
            out[0] = (float)((double)s2 / (double)((long long)NT * NB * NN));
        }
    }
}

extern "C" void kernel_launch(void* const* d_in, const int* in_sizes, int n_in,
                              void* d_out, int out_size, void* d_ws, size_t ws_size,
                              hipStream_t stream) {
    const float* x    = (const float*)d_in[0];  // (32, 500, 1)
    const float* W    = (const float*)d_in[1];  // (2048, 2048)
    const float* bias = (const float*)d_in[2];  // (2048,)
    float* out = (float*)d_out;
    void*  ws  = d_ws;

    void* args[] = { (void*)&x, (void*)&W, (void*)&bias, (void*)&out, (void*)&ws };
    hipLaunchCooperativeKernel((const void*)reservoir_kernel,
                               dim3(NWG), dim3(WGS), args, 0, stream);
}